// Round 1
// baseline (699.700 us; speedup 1.0000x reference)
//
#include <hip/hip_runtime.h>
#include <math.h>

#define BB 4096
#define DD 128

__device__ __forceinline__ unsigned fkey(float x){
    unsigned b = __float_as_uint(x);
    return (b & 0x80000000u) ? ~b : (b | 0x80000000u);
}
__device__ __forceinline__ float funkey(unsigned u){
    unsigned b = (u & 0x80000000u) ? (u & 0x7fffffffu) : ~u;
    return __uint_as_float(b);
}

// ---------- block reductions (256 threads = 4 waves of 64) ----------
__device__ __forceinline__ float blkSumF(float v, volatile float* sh){
    #pragma unroll
    for (int o = 32; o > 0; o >>= 1) v += __shfl_down(v, o);
    int t = threadIdx.x;
    __syncthreads();
    if ((t & 63) == 0) sh[t >> 6] = v;
    __syncthreads();
    return (sh[0] + sh[1]) + (sh[2] + sh[3]);
}
__device__ __forceinline__ float blkMaxF(float v, volatile float* sh){
    #pragma unroll
    for (int o = 32; o > 0; o >>= 1) v = fmaxf(v, __shfl_down(v, o));
    int t = threadIdx.x;
    __syncthreads();
    if ((t & 63) == 0) sh[t >> 6] = v;
    __syncthreads();
    return fmaxf(fmaxf(sh[0], sh[1]), fmaxf(sh[2], sh[3]));
}
__device__ __forceinline__ int blkSumI(int v, volatile int* sh){
    #pragma unroll
    for (int o = 32; o > 0; o >>= 1) v += __shfl_down(v, o);
    int t = threadIdx.x;
    __syncthreads();
    if ((t & 63) == 0) sh[t >> 6] = v;
    __syncthreads();
    return (sh[0] + sh[1]) + (sh[2] + sh[3]);
}

// ---------- normalize: Z[br] = normalize(branch input), br in {drug, se, drug*se} ----------
__global__ void krn_normalize(const float* __restrict__ drug, const float* __restrict__ se,
                              float* __restrict__ Z){
    int row = blockIdx.x, br = blockIdx.y, t = threadIdx.x;  // blockDim = 128
    float dv = drug[row * DD + t];
    float sv = se[row * DD + t];
    float v = (br == 0) ? dv : ((br == 1) ? sv : dv * sv);
    float sq = v * v;
    #pragma unroll
    for (int o = 32; o > 0; o >>= 1) sq += __shfl_down(sq, o);
    __shared__ float sh[2];
    if ((t & 63) == 0) sh[t >> 6] = sq;
    __syncthreads();
    float nrm = sqrtf(sh[0] + sh[1]);
    float dnm = fmaxf(nrm, 1e-12f);
    Z[((size_t)br * BB + row) * DD + t] = v / dnm;
}

// ---------- negative-pair counting (label-only) ----------
__global__ void krn_init(int* __restrict__ ntot){ *ntot = 0; }

__global__ void krn_negcount(const float* __restrict__ labels, int* __restrict__ ntot){
    int i = blockIdx.x, t = threadIdx.x;  // 256 threads
    float li = labels[i];
    int c = 0;
    #pragma unroll
    for (int e = 0; e < BB / 256; ++e){
        int j = t + e * 256;
        float d = fabsf(li - labels[j]);
        if (d > 1.0f) c++;
    }
    __shared__ int sh[4];
    int cc = blkSumI(c, sh);
    if (t == 0) atomicAdd(ntot, cc);
}

__global__ void krn_calck(const int* __restrict__ ntot, int* __restrict__ kflags){
    int N = *ntot;
    // k = trunc((N/4096.0f)*0.5f), exact integer form since N < 2^24
    int k = N >> 13;
    if (k < 1) k = 1;
    if (k > BB - 1) k = BB - 1;
    kflags[0] = k;
    kflags[1] = (N > 0) ? 1 : 0;
}

// ---------- fp32 GEMM: sim[slab rows x BB] = (Z Z^T)/T ----------
__global__ __launch_bounds__(256) void krn_gemm(const float* __restrict__ Z,
                                                float* __restrict__ sim, int r0){
    __shared__ float As[64][64];
    __shared__ float Bs[64][64];
    int t = threadIdx.x;
    int rowbase = r0 + blockIdx.y * 64;
    int colbase = blockIdx.x * 64;
    int lm = t & 63, kq0 = t >> 6;      // loader: row-in-tile, float4-group
    int tx = t & 15, ty = t >> 4;       // compute: 4x4 tile coords
    float acc[4][4] = {{0.f}};

    for (int kc = 0; kc < 2; ++kc){
        #pragma unroll
        for (int c = 0; c < 4; ++c){
            int kq = c * 4 + kq0;       // 0..15
            float4 va = *(const float4*)&Z[(size_t)(rowbase + lm) * DD + kc * 64 + kq * 4];
            As[kq * 4 + 0][lm] = va.x; As[kq * 4 + 1][lm] = va.y;
            As[kq * 4 + 2][lm] = va.z; As[kq * 4 + 3][lm] = va.w;
            float4 vb = *(const float4*)&Z[(size_t)(colbase + lm) * DD + kc * 64 + kq * 4];
            Bs[kq * 4 + 0][lm] = vb.x; Bs[kq * 4 + 1][lm] = vb.y;
            Bs[kq * 4 + 2][lm] = vb.z; Bs[kq * 4 + 3][lm] = vb.w;
        }
        __syncthreads();
        #pragma unroll 8
        for (int k = 0; k < 64; ++k){
            float4 a = *(const float4*)&As[k][ty * 4];
            float4 b = *(const float4*)&Bs[k][tx * 4];
            acc[0][0] += a.x * b.x; acc[0][1] += a.x * b.y; acc[0][2] += a.x * b.z; acc[0][3] += a.x * b.w;
            acc[1][0] += a.y * b.x; acc[1][1] += a.y * b.y; acc[1][2] += a.y * b.z; acc[1][3] += a.y * b.w;
            acc[2][0] += a.z * b.x; acc[2][1] += a.z * b.y; acc[2][2] += a.z * b.z; acc[2][3] += a.z * b.w;
            acc[3][0] += a.w * b.x; acc[3][1] += a.w * b.y; acc[3][2] += a.w * b.z; acc[3][3] += a.w * b.w;
        }
        __syncthreads();
    }

    const float invT = 1.0f / 0.07f;
    #pragma unroll
    for (int r = 0; r < 4; ++r){
        float4 o;
        o.x = acc[r][0] * invT; o.y = acc[r][1] * invT;
        o.z = acc[r][2] * invT; o.w = acc[r][3] * invT;
        *(float4*)&sim[(size_t)(blockIdx.y * 64 + ty * 4 + r) * BB + colbase + tx * 4] = o;
    }
}

// ---------- per-row stats + exact radix top-k select + LSE ----------
__global__ __launch_bounds__(256) void krn_stats(const float* __restrict__ sim,
                                                 const float* __restrict__ labels,
                                                 const int* __restrict__ kflags,
                                                 float* __restrict__ rowloss, int r0){
    __shared__ float srow[BB];
    __shared__ float lab[BB];
    __shared__ int hist[256];
    __shared__ int scn[256];
    __shared__ float redf[4];
    __shared__ int redi[4];
    __shared__ unsigned selb[2];

    int t = threadIdx.x;
    int i = r0 + blockIdx.x;   // global row

    #pragma unroll
    for (int e = 0; e < 4; ++e){
        int j4 = t + e * 256;
        *(float4*)&srow[j4 * 4] = *(const float4*)&sim[((size_t)blockIdx.x) * BB + j4 * 4];
        *(float4*)&lab [j4 * 4] = *(const float4*)&labels[j4 * 4];
    }
    __syncthreads();

    float li = lab[i];
    int kk = kflags[0];
    int anyneg = kflags[1];

    // pass A: max, sum(pw), sum(pw*sim), neg count
    float m = -INFINITY, pwsum = 0.f, pwsim = 0.f;
    int ncnt = 0;
    for (int e = 0; e < 16; ++e){
        int j = t + e * 256;
        float s = srow[j];
        m = fmaxf(m, s);
        float d = fabsf(li - lab[j]);
        if (d > 1.0f) ncnt++;
        if (j != i){
            float pw = expf(-d / 0.15f);
            pwsum += pw;
            pwsim += pw * s;
        }
    }
    float M     = blkMaxF(m, redf);
    float PWS   = blkSumF(pwsum, redf);
    float PWSIM = blkSumF(pwsim, redf);
    int   NC    = blkSumI(ncnt, redi);

    int mode = anyneg ? ((NC <= kk) ? 1 : 0) : 2;  // 0: top-k, 1: all negs, 2: self_mask
    unsigned ukth = 0;
    int r = kk;

    if (mode == 0){
        unsigned prefix = 0;
        for (int level = 3; level >= 0; --level){
            int shl = level * 8;
            hist[t] = 0;
            __syncthreads();
            for (int e = 0; e < 16; ++e){
                int j = t + e * 256;
                float d = fabsf(li - lab[j]);
                if (d > 1.0f){
                    unsigned u = fkey(srow[j]);
                    unsigned hi = (level == 3) ? 0u : (u >> (shl + 8));
                    if (hi == prefix) atomicAdd(&hist[(u >> shl) & 255u], 1);
                }
            }
            __syncthreads();
            // suffix counts via reversed Hillis-Steele inclusive scan
            scn[t] = hist[255 - t];
            __syncthreads();
            for (int o = 1; o < 256; o <<= 1){
                int add = (t >= o) ? scn[t - o] : 0;
                __syncthreads();
                scn[t] += add;
                __syncthreads();
            }
            int b = 255 - t;
            int above_incl = scn[t];
            int above_excl = above_incl - hist[b];
            if (above_excl < r && r <= above_incl){
                selb[0] = (unsigned)b;
                selb[1] = (unsigned)above_excl;
            }
            __syncthreads();
            prefix = (prefix << 8) | selb[0];
            r -= (int)selb[1];
            __syncthreads();
        }
        ukth = prefix;  // exact k-th largest neg sim (as order key); r = #ties included
    }

    // final pass: denominator sum of exp(sim - M) over denom_mask
    float Eloc = 0.f;
    for (int e = 0; e < 16; ++e){
        int j = t + e * 256;
        float s = srow[j];
        bool dm = false;
        if (mode == 2){
            dm = (j != i);
        } else {
            float d = fabsf(li - lab[j]);
            if (d > 1.0f){
                dm = (mode == 1) || (fkey(s) > ukth);
            } else if (j != i){
                float pw = expf(-d / 0.15f);
                dm = (pw > 0.1f);   // hard-neg (d>1) and pw>0.1 (d<0.346) are disjoint
            }
        }
        if (dm) Eloc += expf(s - M);
    }
    float Etot = blkSumF(Eloc, redf);

    if (t == 0){
        if (mode == 0) Etot += (float)r * expf(funkey(ukth) - M);
        float logE = logf(Etot + 1e-8f);
        float S1 = PWSIM - M * PWS;            // sum(pw * logits)
        float w  = S1 - PWS * logE;            // sum(pw * log_prob)
        float dn = fmaxf(PWS, 1e-8f);
        rowloss[i] = w / dn;
    }
}

// ---------- final deterministic reduction ----------
__global__ void krn_final(const float* __restrict__ rowloss, float* __restrict__ out){
    __shared__ float redf[4];
    int t = threadIdx.x;  // 256
    float total = 0.f;
    for (int b = 0; b < 3; ++b){
        float s = 0.f;
        for (int e = 0; e < 16; ++e) s += rowloss[b * BB + t + e * 256];
        float S = blkSumF(s, redf);
        total += S * (1.0f / BB);
    }
    if (t == 0) out[0] = -total / 3.0f;
}

extern "C" void kernel_launch(void* const* d_in, const int* in_sizes, int n_in,
                              void* d_out, int out_size, void* d_ws, size_t ws_size,
                              hipStream_t stream){
    const float* drug   = (const float*)d_in[0];
    const float* se     = (const float*)d_in[1];
    const float* labels = (const float*)d_in[2];
    float* out = (float*)d_out;
    char* ws = (char*)d_ws;

    const size_t zbytes = (size_t)3 * BB * DD * sizeof(float);     // 6 MB
    const size_t tail   = (size_t)3 * BB * sizeof(float) + 256;    // rowloss + scalars

    int slab = 1024;
    while (slab > 64 && zbytes + tail + (size_t)slab * BB * sizeof(float) > ws_size)
        slab >>= 1;

    float* Z       = (float*)ws;
    float* simbuf  = (float*)(ws + zbytes);
    size_t off     = zbytes + (size_t)slab * BB * sizeof(float);
    float* rowloss = (float*)(ws + off);  off += (size_t)3 * BB * sizeof(float);
    int*   ntot    = (int*)(ws + off);
    int*   kflags  = ntot + 2;

    krn_normalize<<<dim3(BB, 3), 128, 0, stream>>>(drug, se, Z);
    krn_init<<<1, 1, 0, stream>>>(ntot);
    krn_negcount<<<BB, 256, 0, stream>>>(labels, ntot);
    krn_calck<<<1, 1, 0, stream>>>(ntot, kflags);

    int nslab = BB / slab;
    for (int b = 0; b < 3; ++b){
        const float* Zb = Z + (size_t)b * BB * DD;
        for (int s = 0; s < nslab; ++s){
            krn_gemm<<<dim3(BB / 64, slab / 64), 256, 0, stream>>>(Zb, simbuf, s * slab);
            krn_stats<<<slab, 256, 0, stream>>>(simbuf, labels, kflags, rowloss + b * BB, s * slab);
        }
    }
    krn_final<<<1, 256, 0, stream>>>(rowloss, out);
}

// Round 2
// 208.252 us; speedup vs baseline: 3.3599x; 3.3599x over previous
//
#include <hip/hip_runtime.h>
#include <math.h>

#define BB 4096
#define DD 128

typedef __attribute__((ext_vector_type(8))) short bf16x8;
typedef __attribute__((ext_vector_type(4))) float f32x4;

__device__ __forceinline__ unsigned fkey(float x){
    unsigned b = __float_as_uint(x);
    return (b & 0x80000000u) ? ~b : (b | 0x80000000u);
}
__device__ __forceinline__ float funkey(unsigned u){
    unsigned b = (u & 0x80000000u) ? (u & 0x7fffffffu) : ~u;
    return __uint_as_float(b);
}

// ---------- block reductions (256 threads = 4 waves of 64) ----------
__device__ __forceinline__ float blkSumF(float v, volatile float* sh){
    #pragma unroll
    for (int o = 32; o > 0; o >>= 1) v += __shfl_down(v, o);
    int t = threadIdx.x;
    __syncthreads();
    if ((t & 63) == 0) sh[t >> 6] = v;
    __syncthreads();
    return (sh[0] + sh[1]) + (sh[2] + sh[3]);
}
__device__ __forceinline__ float blkMaxF(float v, volatile float* sh){
    #pragma unroll
    for (int o = 32; o > 0; o >>= 1) v = fmaxf(v, __shfl_down(v, o));
    int t = threadIdx.x;
    __syncthreads();
    if ((t & 63) == 0) sh[t >> 6] = v;
    __syncthreads();
    return fmaxf(fmaxf(sh[0], sh[1]), fmaxf(sh[2], sh[3]));
}
__device__ __forceinline__ int blkSumI(int v, volatile int* sh){
    #pragma unroll
    for (int o = 32; o > 0; o >>= 1) v += __shfl_down(v, o);
    int t = threadIdx.x;
    __syncthreads();
    if ((t & 63) == 0) sh[t >> 6] = v;
    __syncthreads();
    return (sh[0] + sh[1]) + (sh[2] + sh[3]);
}

// ---------- normalize -> bf16, stored with XOR-swizzled column (T2 swizzle) ----------
// G[row*128 + (col ^ ((row&7)<<3))] = bf16(z[row][col])
__global__ void krn_normalize(const float* __restrict__ drug, const float* __restrict__ se,
                              ushort* __restrict__ Z){
    int row = blockIdx.x, br = blockIdx.y, t = threadIdx.x;  // blockDim = 128
    float dv = drug[row * DD + t];
    float sv = se[row * DD + t];
    float v = (br == 0) ? dv : ((br == 1) ? sv : dv * sv);
    float sq = v * v;
    #pragma unroll
    for (int o = 32; o > 0; o >>= 1) sq += __shfl_down(sq, o);
    __shared__ float sh[2];
    if ((t & 63) == 0) sh[t >> 6] = sq;
    __syncthreads();
    float nrm = sqrtf(sh[0] + sh[1]);
    float outv = v / fmaxf(nrm, 1e-12f);
    // round-to-nearest-even bf16
    unsigned u = __float_as_uint(outv);
    unsigned r = (u + 0x7FFFu + ((u >> 16) & 1u)) >> 16;
    int col = t ^ ((row & 7) << 3);
    Z[((size_t)br * BB + row) * DD + col] = (ushort)r;
}

// ---------- negative-pair counting (label-only), LDS-cached ----------
__global__ void krn_init(int* __restrict__ ntot){ *ntot = 0; }

__global__ __launch_bounds__(256) void krn_negcount(const float* __restrict__ labels,
                                                    int* __restrict__ ntot){
    __shared__ float lab[BB];
    __shared__ int shi[4];
    int t = threadIdx.x;
    #pragma unroll
    for (int e = 0; e < 4; ++e)
        ((float4*)lab)[t + e * 256] = ((const float4*)labels)[t + e * 256];
    __syncthreads();
    int i0 = blockIdx.x * 16;   // 256 blocks x 16 rows
    int c = 0;
    for (int ii = 0; ii < 16; ++ii){
        float li = lab[i0 + ii];
        #pragma unroll
        for (int e = 0; e < 16; ++e){
            int j = t + e * 256;
            c += (fabsf(li - lab[j]) > 1.0f) ? 1 : 0;
        }
    }
    int cc = blkSumI(c, shi);
    if (t == 0) atomicAdd(ntot, cc);
}

__global__ void krn_calck(const int* __restrict__ ntot, int* __restrict__ kflags){
    int N = *ntot;
    int k = N >> 13;            // trunc((N/4096)*0.5), exact
    if (k < 1) k = 1;
    if (k > BB - 1) k = BB - 1;
    kflags[0] = k;
    kflags[1] = (N > 0) ? 1 : 0;
}

// ---------- bf16 MFMA GEMM: sim[slab x BB] = (Z Z^T)/T ----------
__device__ __forceinline__ bf16x8 frag_ld(const ushort* base, int row, int e0){
    int e = e0 ^ ((row & 7) << 3);
    return *(const bf16x8*)(base + row * DD + e);
}

__global__ __launch_bounds__(256) void krn_gemm(const ushort* __restrict__ Zb,
                                                float* __restrict__ sim, int r0){
    __shared__ ushort As[128 * DD];
    __shared__ ushort Bs[128 * DD];
    int t = threadIdx.x;
    int rowbase = r0 + blockIdx.y * 128;
    int colbase = blockIdx.x * 128;

    // stage both 32KB tiles: contiguous copies (global is pre-swizzled)
    {
        const float4* gA = (const float4*)(Zb + (size_t)rowbase * DD);
        const float4* gB = (const float4*)(Zb + (size_t)colbase * DD);
        float4* lA = (float4*)As;
        float4* lB = (float4*)Bs;
        #pragma unroll
        for (int it = 0; it < 8; ++it){
            lA[it * 256 + t] = gA[it * 256 + t];
            lB[it * 256 + t] = gB[it * 256 + t];
        }
    }
    __syncthreads();

    int wid = t >> 6, lane = t & 63;
    int wr = (wid >> 1) * 64, wc = (wid & 1) * 64;
    int fr = lane & 15, fq = lane >> 4;

    f32x4 acc[4][4];
    #pragma unroll
    for (int m = 0; m < 4; ++m)
        #pragma unroll
        for (int n = 0; n < 4; ++n)
            acc[m][n] = (f32x4){0.f, 0.f, 0.f, 0.f};

    #pragma unroll
    for (int ks = 0; ks < 4; ++ks){
        int e0 = ks * 32 + fq * 8;
        bf16x8 a0 = frag_ld(As, wr + 0 * 16 + fr, e0);
        bf16x8 a1 = frag_ld(As, wr + 1 * 16 + fr, e0);
        bf16x8 a2 = frag_ld(As, wr + 2 * 16 + fr, e0);
        bf16x8 a3 = frag_ld(As, wr + 3 * 16 + fr, e0);
        bf16x8 b0 = frag_ld(Bs, wc + 0 * 16 + fr, e0);
        bf16x8 b1 = frag_ld(Bs, wc + 1 * 16 + fr, e0);
        bf16x8 b2 = frag_ld(Bs, wc + 2 * 16 + fr, e0);
        bf16x8 b3 = frag_ld(Bs, wc + 3 * 16 + fr, e0);
        acc[0][0] = __builtin_amdgcn_mfma_f32_16x16x32_bf16(a0, b0, acc[0][0], 0, 0, 0);
        acc[0][1] = __builtin_amdgcn_mfma_f32_16x16x32_bf16(a0, b1, acc[0][1], 0, 0, 0);
        acc[0][2] = __builtin_amdgcn_mfma_f32_16x16x32_bf16(a0, b2, acc[0][2], 0, 0, 0);
        acc[0][3] = __builtin_amdgcn_mfma_f32_16x16x32_bf16(a0, b3, acc[0][3], 0, 0, 0);
        acc[1][0] = __builtin_amdgcn_mfma_f32_16x16x32_bf16(a1, b0, acc[1][0], 0, 0, 0);
        acc[1][1] = __builtin_amdgcn_mfma_f32_16x16x32_bf16(a1, b1, acc[1][1], 0, 0, 0);
        acc[1][2] = __builtin_amdgcn_mfma_f32_16x16x32_bf16(a1, b2, acc[1][2], 0, 0, 0);
        acc[1][3] = __builtin_amdgcn_mfma_f32_16x16x32_bf16(a1, b3, acc[1][3], 0, 0, 0);
        acc[2][0] = __builtin_amdgcn_mfma_f32_16x16x32_bf16(a2, b0, acc[2][0], 0, 0, 0);
        acc[2][1] = __builtin_amdgcn_mfma_f32_16x16x32_bf16(a2, b1, acc[2][1], 0, 0, 0);
        acc[2][2] = __builtin_amdgcn_mfma_f32_16x16x32_bf16(a2, b2, acc[2][2], 0, 0, 0);
        acc[2][3] = __builtin_amdgcn_mfma_f32_16x16x32_bf16(a2, b3, acc[2][3], 0, 0, 0);
        acc[3][0] = __builtin_amdgcn_mfma_f32_16x16x32_bf16(a3, b0, acc[3][0], 0, 0, 0);
        acc[3][1] = __builtin_amdgcn_mfma_f32_16x16x32_bf16(a3, b1, acc[3][1], 0, 0, 0);
        acc[3][2] = __builtin_amdgcn_mfma_f32_16x16x32_bf16(a3, b2, acc[3][2], 0, 0, 0);
        acc[3][3] = __builtin_amdgcn_mfma_f32_16x16x32_bf16(a3, b3, acc[3][3], 0, 0, 0);
    }

    const float invT = 1.0f / 0.07f;
    int srow0 = blockIdx.y * 128 + wr + fq * 4;
    int scol0 = colbase + wc + fr;
    #pragma unroll
    for (int m = 0; m < 4; ++m){
        #pragma unroll
        for (int n = 0; n < 4; ++n){
            f32x4 c = acc[m][n];
            #pragma unroll
            for (int j = 0; j < 4; ++j)
                sim[(size_t)(srow0 + m * 16 + j) * BB + scol0 + n * 16] = c[j] * invT;
        }
    }
}

// ---------- per-row stats + exact radix top-k select + LSE (register-resident) ----------
__global__ __launch_bounds__(256) void krn_stats(const float* __restrict__ sim,
                                                 const float* __restrict__ labels,
                                                 const int* __restrict__ kflags,
                                                 float* __restrict__ rowloss, int r0){
    __shared__ int hist[256];
    __shared__ int wsum[4];
    __shared__ float redf[4];
    __shared__ int redi[4];
    __shared__ unsigned selb[2];

    int t = threadIdx.x;
    int i = r0 + blockIdx.x;
    float li = labels[i];

    hist[t] = 0;
    __syncthreads();

    float s[16];
    unsigned negbits = 0, posbits = 0, selfbits = 0;
    float m = -INFINITY, pwsum = 0.f, pwsim = 0.f;
    int ncnt = 0;

    const float4* srow4 = (const float4*)(sim + (size_t)blockIdx.x * BB);
    const float4* lab4  = (const float4*)labels;

    #pragma unroll
    for (int e = 0; e < 4; ++e){
        float4 sv = srow4[t + e * 256];
        float4 lv = lab4[t + e * 256];
        int jbase = (t + e * 256) * 4;
        float ss[4] = {sv.x, sv.y, sv.z, sv.w};
        float ll[4] = {lv.x, lv.y, lv.z, lv.w};
        #pragma unroll
        for (int c = 0; c < 4; ++c){
            int idx = e * 4 + c;
            float val = ss[c];
            s[idx] = val;
            m = fmaxf(m, val);
            float d = fabsf(li - ll[c]);
            int j = jbase + c;
            if (d > 1.0f){
                negbits |= 1u << idx;
                ncnt++;
                atomicAdd(&hist[fkey(val) >> 24], 1);   // fused level-3 histogram
            }
            if (j == i){
                selfbits |= 1u << idx;
            } else {
                float pw = __expf(d * (-1.0f / 0.15f));
                pwsum += pw;
                pwsim += pw * val;
                if (d < 0.34538776f) posbits |= 1u << idx;   // pw > 0.1
            }
        }
    }

    float M     = blkMaxF(m, redf);
    float PWS   = blkSumF(pwsum, redf);
    float PWSIM = blkSumF(pwsim, redf);
    int   NC    = blkSumI(ncnt, redi);

    int kk = kflags[0];
    int anyneg = kflags[1];
    int mode = anyneg ? ((NC <= kk) ? 1 : 0) : 2;  // 0: top-k, 1: all negs, 2: self_mask
    unsigned ukth = 0;
    int r = kk;

    if (mode == 0){
        unsigned prefix = 0;
        for (int level = 3; level >= 0; --level){
            int shl = level * 8;
            if (level < 3){
                hist[t] = 0;
                __syncthreads();
                #pragma unroll
                for (int idx = 0; idx < 16; ++idx){
                    if (negbits & (1u << idx)){
                        unsigned u = fkey(s[idx]);
                        if ((u >> (shl + 8)) == prefix)
                            atomicAdd(&hist[(u >> shl) & 255u], 1);
                    }
                }
                __syncthreads();
            }
            // suffix count via wave shuffle scan (bins processed high->low)
            int b = 255 - t;
            int hv = hist[b];
            int v = hv;
            #pragma unroll
            for (int o = 1; o < 64; o <<= 1){
                int u2 = __shfl_up(v, o);
                if ((t & 63) >= o) v += u2;
            }
            if ((t & 63) == 63) wsum[t >> 6] = v;
            __syncthreads();
            int w = t >> 6;
            int pre = (w > 0 ? wsum[0] : 0) + (w > 1 ? wsum[1] : 0) + (w > 2 ? wsum[2] : 0);
            v += pre;
            int above_excl = v - hv;
            if (above_excl < r && r <= v){
                selb[0] = (unsigned)b;
                selb[1] = (unsigned)above_excl;
            }
            __syncthreads();
            prefix = (prefix << 8) | selb[0];
            r -= (int)selb[1];
            __syncthreads();
        }
        ukth = prefix;
    }

    // denominator: sum exp(s - M) over denom mask
    float El = 0.f;
    unsigned em;
    if (mode == 2)      em = 0xFFFFu & ~selfbits;
    else if (mode == 1) em = negbits | posbits;
    else                em = posbits;
    #pragma unroll
    for (int idx = 0; idx < 16; ++idx)
        if (em & (1u << idx)) El += __expf(s[idx] - M);
    if (mode == 0){
        #pragma unroll
        for (int idx = 0; idx < 16; ++idx)
            if ((negbits & (1u << idx)) && fkey(s[idx]) > ukth)
                El += __expf(s[idx] - M);
    }
    float Etot = blkSumF(El, redf);

    if (t == 0){
        if (mode == 0) Etot += (float)r * __expf(funkey(ukth) - M);
        float logE = __logf(Etot + 1e-8f);
        float w  = (PWSIM - M * PWS) - PWS * logE;
        float dn = fmaxf(PWS, 1e-8f);
        rowloss[i] = w / dn;
    }
}

// ---------- final deterministic reduction ----------
__global__ void krn_final(const float* __restrict__ rowloss, float* __restrict__ out){
    __shared__ float redf[4];
    int t = threadIdx.x;  // 256
    float total = 0.f;
    for (int b = 0; b < 3; ++b){
        float ssum = 0.f;
        for (int e = 0; e < 16; ++e) ssum += rowloss[b * BB + t + e * 256];
        float S = blkSumF(ssum, redf);
        total += S * (1.0f / BB);
    }
    if (t == 0) out[0] = -total / 3.0f;
}

extern "C" void kernel_launch(void* const* d_in, const int* in_sizes, int n_in,
                              void* d_out, int out_size, void* d_ws, size_t ws_size,
                              hipStream_t stream){
    const float* drug   = (const float*)d_in[0];
    const float* se     = (const float*)d_in[1];
    const float* labels = (const float*)d_in[2];
    float* out = (float*)d_out;
    char* ws = (char*)d_ws;

    const size_t zbytes = (size_t)3 * BB * DD * sizeof(ushort);    // 3 MB bf16
    const size_t tail   = (size_t)3 * BB * sizeof(float) + 256;

    int slab = BB;
    while (slab > 128 && zbytes + tail + (size_t)slab * BB * sizeof(float) > ws_size)
        slab >>= 1;

    ushort* Z      = (ushort*)ws;
    float* simbuf  = (float*)(ws + zbytes);
    size_t off     = zbytes + (size_t)slab * BB * sizeof(float);
    float* rowloss = (float*)(ws + off);  off += (size_t)3 * BB * sizeof(float);
    int*   ntot    = (int*)(ws + off);
    int*   kflags  = ntot + 2;

    krn_normalize<<<dim3(BB, 3), 128, 0, stream>>>(drug, se, Z);
    krn_init<<<1, 1, 0, stream>>>(ntot);
    krn_negcount<<<256, 256, 0, stream>>>(labels, ntot);
    krn_calck<<<1, 1, 0, stream>>>(ntot, kflags);

    int nslab = BB / slab;
    for (int b = 0; b < 3; ++b){
        const ushort* Zb = Z + (size_t)b * BB * DD;
        for (int s2 = 0; s2 < nslab; ++s2){
            krn_gemm<<<dim3(BB / 128, slab / 128), 256, 0, stream>>>(Zb, simbuf, s2 * slab);
            krn_stats<<<slab, 256, 0, stream>>>(simbuf, labels, kflags, rowloss + b * BB, s2 * slab);
        }
    }
    krn_final<<<1, 256, 0, stream>>>(rowloss, out);
}